// Round 1
// baseline (2176.687 us; speedup 1.0000x reference)
//
#include <hip/hip_runtime.h>
#include <math.h>

#define H 256
#define W 256
#define HW (H * W)
#define B 2
#define V 3
#define BV (B * V)
#define C 32
#define RADIUS 1.5f
#define TAU 1.0f
#define EPS 1e-8f

// ---------------------------------------------------------------------------
// Setup: per (b,v) fold the projection chain into one matrix
//   M = K[b] * dst_RT[b] * src_RTinv[b,v] * inv(K[b])
// ---------------------------------------------------------------------------
__global__ void setup_kernel(const float* __restrict__ Kmat,
                             const float* __restrict__ srcRTinv,
                             const float* __restrict__ dstRT,
                             float* __restrict__ Mbuf) {
    int bv = threadIdx.x;
    if (bv >= BV) return;
    int b = bv / V;

    // Gauss-Jordan 4x4 inverse of K[b] with partial pivoting
    float a[4][8];
    for (int i = 0; i < 4; i++)
        for (int j = 0; j < 4; j++) {
            a[i][j] = Kmat[b * 16 + i * 4 + j];
            a[i][4 + j] = (i == j) ? 1.0f : 0.0f;
        }
    for (int col = 0; col < 4; col++) {
        int piv = col;
        float best = fabsf(a[col][col]);
        for (int r = col + 1; r < 4; r++) {
            float v = fabsf(a[r][col]);
            if (v > best) { best = v; piv = r; }
        }
        if (piv != col) {
            for (int j = 0; j < 8; j++) {
                float t = a[col][j]; a[col][j] = a[piv][j]; a[piv][j] = t;
            }
        }
        float s = 1.0f / a[col][col];
        for (int j = 0; j < 8; j++) a[col][j] *= s;
        for (int r = 0; r < 4; r++) {
            if (r == col) continue;
            float m = a[r][col];
            for (int j = 0; j < 8; j++) a[r][j] -= m * a[col][j];
        }
    }
    float Kinv[16];
    for (int i = 0; i < 4; i++)
        for (int j = 0; j < 4; j++) Kinv[i * 4 + j] = a[i][4 + j];

    // T1 = srcRTinv[bv] * Kinv
    float T1[16];
    const float* S = srcRTinv + bv * 16;
    for (int i = 0; i < 4; i++)
        for (int j = 0; j < 4; j++) {
            float acc = 0.0f;
            for (int k = 0; k < 4; k++) acc += S[i * 4 + k] * Kinv[k * 4 + j];
            T1[i * 4 + j] = acc;
        }
    // T2 = dstRT[b,0] * T1
    float T2[16];
    const float* D = dstRT + b * 16;
    for (int i = 0; i < 4; i++)
        for (int j = 0; j < 4; j++) {
            float acc = 0.0f;
            for (int k = 0; k < 4; k++) acc += D[i * 4 + k] * T1[k * 4 + j];
            T2[i * 4 + j] = acc;
        }
    // M = K[b] * T2
    const float* Kb = Kmat + b * 16;
    for (int i = 0; i < 4; i++)
        for (int j = 0; j < 4; j++) {
            float acc = 0.0f;
            for (int k = 0; k < 4; k++) acc += Kb[i * 4 + k] * T2[k * 4 + j];
            Mbuf[bv * 16 + i * 4 + j] = acc;
        }
}

// ---------------------------------------------------------------------------
// Splat: one thread per source point. Projection + 9-tap scatter-add.
//   fout  : (BV, C, H, W) feature-weight accumulator (in d_out, pre-zeroed)
//   wsum  : (BV, H, W) weight accumulator (in ws, pre-zeroed)
//   zsum  : (BV, H, W) depth-weight accumulator (in ws, pre-zeroed)
// ---------------------------------------------------------------------------
__global__ __launch_bounds__(256) void splat_kernel(
    const float* __restrict__ depths, const float* __restrict__ feats,
    const float* __restrict__ Mbuf, float* __restrict__ fout,
    float* __restrict__ wsum, float* __restrict__ zsum) {
    int gid = blockIdx.x * blockDim.x + threadIdx.x;
    if (gid >= BV * HW) return;
    int bv = gid >> 16;
    int n = gid & (HW - 1);
    int pxi = n & (W - 1);
    int pyi = n >> 8;

    float xn = (float)pxi * (2.0f / (W - 1)) - 1.0f;
    float yn = (float)pyi * (2.0f / (H - 1)) - 1.0f;
    float d = depths[gid];

    const float* M = Mbuf + bv * 16;
    float X = xn * d, Y = yn * d;
    float p0 = M[0] * X + M[1] * Y + M[2] * d + M[3];
    float p1 = M[4] * X + M[5] * Y + M[6] * d + M[7];
    float z  = M[8] * X + M[9] * Y + M[10] * d + M[11];

    float inv = 1.0f / (z + EPS);
    bool zpos = z > 0.0f;
    float xp = zpos ? p0 * inv : -10.0f;
    float yp = zpos ? p1 * inv : -10.0f;

    float px = (xp + 1.0f) * 0.5f * (float)(W - 1);
    float py = (yp + 1.0f) * 0.5f * (float)(H - 1);
    float rx = rintf(px);  // round-half-even, matches jnp.round
    float ry = rintf(py);
    float wd = expf(-TAU * z);

    // cache the 32 feature values in registers (coalesced loads per channel)
    float f[C];
#pragma unroll
    for (int c = 0; c < C; c++) f[c] = feats[((size_t)bv * C + c) * HW + n];

    float* fbase = fout + (size_t)bv * C * HW;
    float* wbase = wsum + (size_t)bv * HW;
    float* zbase = zsum + (size_t)bv * HW;

#pragma unroll
    for (int dy = -1; dy <= 1; dy++) {
        float iy = ry + (float)dy;
#pragma unroll
        for (int dx = -1; dx <= 1; dx++) {
            float ix = rx + (float)dx;
            float ddx = ix - px, ddy = iy - py;
            float dist = sqrtf(ddx * ddx + ddy * ddy + EPS);
            float wr = fmaxf(0.0f, 1.0f - dist / RADIUS);
            bool valid = (ix >= 0.0f) && (ix < (float)W) && (iy >= 0.0f) &&
                         (iy < (float)H) && zpos;
            float w = wr * wd;
            if (valid && w > 0.0f) {
                int pix = (int)iy * W + (int)ix;
                atomicAdd(wbase + pix, w);
                atomicAdd(zbase + pix, z * w);
                float* fp = fbase + pix;
#pragma unroll
                for (int c = 0; c < C; c++) atomicAdd(fp + c * HW, f[c] * w);
            }
        }
    }
}

// ---------------------------------------------------------------------------
// Normalize: out_f = f_sum/(w+eps), out_d = z_sum/(w+eps)
// ---------------------------------------------------------------------------
__global__ __launch_bounds__(256) void norm_kernel(const float* __restrict__ wsum,
                                                   const float* __restrict__ zsum,
                                                   float* __restrict__ out) {
    int gid = blockIdx.x * blockDim.x + threadIdx.x;
    if (gid >= BV * HW) return;
    int bv = gid >> 16;
    int n = gid & (HW - 1);
    float invw = 1.0f / (wsum[gid] + EPS);
    float* fp = out + (size_t)bv * C * HW + n;
#pragma unroll
    for (int c = 0; c < C; c++) fp[c * HW] *= invw;
    out[(size_t)BV * C * HW + gid] = zsum[gid] * invw;
}

extern "C" void kernel_launch(void* const* d_in, const int* in_sizes, int n_in,
                              void* d_out, int out_size, void* d_ws, size_t ws_size,
                              hipStream_t stream) {
    const float* depths   = (const float*)d_in[0];  // (B,V,1,H,W)
    const float* feats    = (const float*)d_in[1];  // (B,V,C,H,W)
    const float* Kmat     = (const float*)d_in[2];  // (B,4,4)
    const float* srcRTinv = (const float*)d_in[4];  // (B,V,4,4)
    const float* dstRT    = (const float*)d_in[5];  // (B,1,4,4)

    float* out = (float*)d_out;
    // ws layout: wsum (BV*HW) | zsum (BV*HW) | Mbuf (BV*16)
    float* wsum = (float*)d_ws;
    float* zsum = wsum + (size_t)BV * HW;
    float* Mbuf = zsum + (size_t)BV * HW;

    // zero accumulators: feature region of d_out + wsum/zsum in ws
    hipMemsetAsync(d_out, 0, (size_t)BV * C * HW * sizeof(float), stream);
    hipMemsetAsync(d_ws, 0, (size_t)2 * BV * HW * sizeof(float), stream);

    setup_kernel<<<1, 64, 0, stream>>>(Kmat, srcRTinv, dstRT, Mbuf);

    int total = BV * HW;
    splat_kernel<<<total / 256, 256, 0, stream>>>(depths, feats, Mbuf, out, wsum, zsum);
    norm_kernel<<<total / 256, 256, 0, stream>>>(wsum, zsum, out);
}

// Round 2
// 690.462 us; speedup vs baseline: 3.1525x; 3.1525x over previous
//
#include <hip/hip_runtime.h>
#include <math.h>

#define H 256
#define W 256
#define HW (H * W)
#define B 2
#define V 3
#define BV (B * V)
#define C 32
#define RADIUS 1.5f
#define TAU 1.0f
#define EPS 1e-8f

#define TS 16                 // destination tile edge
#define NTX (W / TS)          // 16
#define NTY (H / TS)          // 16
#define TPB (NTX * NTY)       // 256 tiles per image
#define NT (BV * TPB)         // 1536 tiles total
#define ACC_STRIDE 33         // pad 32->33 to break LDS bank conflicts

// ---------------------------------------------------------------------------
// Setup: per (b,v) fold the projection chain into one matrix
//   M = K[b] * dst_RT[b] * src_RTinv[b,v] * inv(K[b])
// ---------------------------------------------------------------------------
__global__ void setup_kernel(const float* __restrict__ Kmat,
                             const float* __restrict__ srcRTinv,
                             const float* __restrict__ dstRT,
                             float* __restrict__ Mbuf) {
    int bv = threadIdx.x;
    if (bv >= BV) return;
    int b = bv / V;

    float a[4][8];
    for (int i = 0; i < 4; i++)
        for (int j = 0; j < 4; j++) {
            a[i][j] = Kmat[b * 16 + i * 4 + j];
            a[i][4 + j] = (i == j) ? 1.0f : 0.0f;
        }
    for (int col = 0; col < 4; col++) {
        int piv = col;
        float best = fabsf(a[col][col]);
        for (int r = col + 1; r < 4; r++) {
            float v = fabsf(a[r][col]);
            if (v > best) { best = v; piv = r; }
        }
        if (piv != col) {
            for (int j = 0; j < 8; j++) {
                float t = a[col][j]; a[col][j] = a[piv][j]; a[piv][j] = t;
            }
        }
        float s = 1.0f / a[col][col];
        for (int j = 0; j < 8; j++) a[col][j] *= s;
        for (int r = 0; r < 4; r++) {
            if (r == col) continue;
            float m = a[r][col];
            for (int j = 0; j < 8; j++) a[r][j] -= m * a[col][j];
        }
    }
    float Kinv[16];
    for (int i = 0; i < 4; i++)
        for (int j = 0; j < 4; j++) Kinv[i * 4 + j] = a[i][4 + j];

    float T1[16];
    const float* S = srcRTinv + bv * 16;
    for (int i = 0; i < 4; i++)
        for (int j = 0; j < 4; j++) {
            float acc = 0.0f;
            for (int k = 0; k < 4; k++) acc += S[i * 4 + k] * Kinv[k * 4 + j];
            T1[i * 4 + j] = acc;
        }
    float T2[16];
    const float* D = dstRT + b * 16;
    for (int i = 0; i < 4; i++)
        for (int j = 0; j < 4; j++) {
            float acc = 0.0f;
            for (int k = 0; k < 4; k++) acc += D[i * 4 + k] * T1[k * 4 + j];
            T2[i * 4 + j] = acc;
        }
    const float* Kb = Kmat + b * 16;
    for (int i = 0; i < 4; i++)
        for (int j = 0; j < 4; j++) {
            float acc = 0.0f;
            for (int k = 0; k < 4; k++) acc += Kb[i * 4 + k] * T2[k * 4 + j];
            Mbuf[bv * 16 + i * 4 + j] = acc;
        }
}

// Compute clipped 3x3 footprint box -> touched tile range. Returns false if none.
__device__ __forceinline__ bool footprint_tiles(float px, float py, float z,
                                                int& tx0, int& tx1, int& ty0,
                                                int& ty1) {
    if (!(z > 0.0f)) return false;
    float rxC = fminf(fmaxf(rintf(px), -4.0f), 260.0f);
    float ryC = fminf(fmaxf(rintf(py), -4.0f), 260.0f);
    int x0 = max((int)rxC - 1, 0), x1 = min((int)rxC + 1, W - 1);
    int y0 = max((int)ryC - 1, 0), y1 = min((int)ryC + 1, H - 1);
    if (x0 > x1 || y0 > y1) return false;
    tx0 = x0 >> 4; tx1 = x1 >> 4; ty0 = y0 >> 4; ty1 = y1 >> 4;
    return true;
}

// ---------------------------------------------------------------------------
// Phase 1: project every source point, store (px,py,z,wd), count per tile.
// ---------------------------------------------------------------------------
__global__ __launch_bounds__(256) void project_count_kernel(
    const float* __restrict__ depths, const float* __restrict__ Mbuf,
    float4* __restrict__ proj4, int* __restrict__ counts) {
    __shared__ int hist[TPB];
    int tid = threadIdx.x;
    hist[tid] = 0;
    __syncthreads();

    int gid = blockIdx.x * 256 + tid;
    int bv = gid >> 16;
    int n = gid & (HW - 1);
    int pxi = n & (W - 1);
    int pyi = n >> 8;

    float xn = (float)pxi * (2.0f / (W - 1)) - 1.0f;
    float yn = (float)pyi * (2.0f / (H - 1)) - 1.0f;
    float d = depths[gid];
    const float* M = Mbuf + bv * 16;
    float X = xn * d, Y = yn * d;
    float p0 = M[0] * X + M[1] * Y + M[2] * d + M[3];
    float p1 = M[4] * X + M[5] * Y + M[6] * d + M[7];
    float z  = M[8] * X + M[9] * Y + M[10] * d + M[11];

    bool zpos = z > 0.0f;
    float inv = 1.0f / (z + EPS);
    float xp = zpos ? p0 * inv : -10.0f;
    float yp = zpos ? p1 * inv : -10.0f;
    float px = (xp + 1.0f) * 0.5f * (float)(W - 1);
    float py = (yp + 1.0f) * 0.5f * (float)(H - 1);
    float wd = expf(-TAU * z);
    proj4[gid] = make_float4(px, py, z, wd);

    int tx0, tx1, ty0, ty1;
    if (footprint_tiles(px, py, z, tx0, tx1, ty0, ty1)) {
        for (int ty = ty0; ty <= ty1; ty++)
            for (int tx = tx0; tx <= tx1; tx++)
                atomicAdd(&hist[ty * NTX + tx], 1);
    }
    __syncthreads();
    if (hist[tid] > 0) atomicAdd(&counts[(bv << 8) + tid], hist[tid]);
}

// ---------------------------------------------------------------------------
// Phase 2: exclusive scan of 1536 tile counts (single block).
// ---------------------------------------------------------------------------
__global__ __launch_bounds__(256) void scan_kernel(const int* __restrict__ counts,
                                                   int* __restrict__ offsets,
                                                   int* __restrict__ cursors) {
    __shared__ int sums[256];
    int t = threadIdx.x;
    int v[6];
    int s = 0;
    for (int k = 0; k < 6; k++) { v[k] = counts[t * 6 + k]; s += v[k]; }
    sums[t] = s;
    __syncthreads();
    for (int off = 1; off < 256; off <<= 1) {
        int x = (t >= off) ? sums[t - off] : 0;
        __syncthreads();
        sums[t] += x;
        __syncthreads();
    }
    int base = (t > 0) ? sums[t - 1] : 0;
    for (int k = 0; k < 6; k++) {
        offsets[t * 6 + k] = base;
        cursors[t * 6 + k] = base;
        base += v[k];
    }
    if (t == 255) offsets[NT] = base;
}

// ---------------------------------------------------------------------------
// Phase 3: fill per-tile source lists (block-aggregated reservation).
// ---------------------------------------------------------------------------
__global__ __launch_bounds__(256) void fill_kernel(const float4* __restrict__ proj4,
                                                   int* __restrict__ cursors,
                                                   int* __restrict__ bins) {
    __shared__ int hist[TPB];
    __shared__ int basear[TPB];
    int tid = threadIdx.x;
    hist[tid] = 0;
    __syncthreads();

    int gid = blockIdx.x * 256 + tid;
    int bv = gid >> 16;
    int n = gid & (HW - 1);
    float4 p = proj4[gid];

    int lt[4], lofs[4], cnt = 0;
    int tx0, tx1, ty0, ty1;
    if (footprint_tiles(p.x, p.y, p.z, tx0, tx1, ty0, ty1)) {
        for (int ty = ty0; ty <= ty1; ty++)
            for (int tx = tx0; tx <= tx1; tx++) {
                int l = ty * NTX + tx;
                lofs[cnt] = atomicAdd(&hist[l], 1);
                lt[cnt] = l;
                cnt++;
            }
    }
    __syncthreads();
    if (hist[tid] > 0) basear[tid] = atomicAdd(&cursors[(bv << 8) + tid], hist[tid]);
    __syncthreads();
    for (int j = 0; j < cnt; j++) bins[basear[lt[j]] + lofs[j]] = n;
}

// ---------------------------------------------------------------------------
// Phase 4: per-tile LDS accumulation + fused normalize + store.
// Tiles partition the image, so no global atomics and every output element
// is written exactly once.
// ---------------------------------------------------------------------------
__global__ __launch_bounds__(256) void accum_kernel(
    const float4* __restrict__ proj4, const float* __restrict__ feats,
    const int* __restrict__ offsets, const int* __restrict__ bins,
    float* __restrict__ out) {
    __shared__ float accw[TS * TS];
    __shared__ float accz[TS * TS];
    __shared__ float accf[TS * TS * ACC_STRIDE];

    int tid = threadIdx.x;
    int tile = blockIdx.x;
    int bv = tile >> 8;
    int t = tile & 255;
    int tileX0 = (t & 15) << 4;
    int tileY0 = (t >> 4) << 4;

    accw[tid] = 0.0f;
    accz[tid] = 0.0f;
    for (int i = tid; i < TS * TS * ACC_STRIDE; i += 256) accf[i] = 0.0f;
    __syncthreads();

    int start = offsets[tile], end = offsets[tile + 1];
    for (int i = start + tid; i < end; i += 256) {
        int n = bins[i];
        float4 p = proj4[(bv << 16) + n];
        float rx = rintf(p.x), ry = rintf(p.y);

        float wtap[9];
        int pltap[9];
        int nh = 0;
#pragma unroll
        for (int dy = -1; dy <= 1; dy++) {
#pragma unroll
            for (int dx = -1; dx <= 1; dx++) {
                float ix = rx + (float)dx, iy = ry + (float)dy;
                float lxf = ix - (float)tileX0, lyf = iy - (float)tileY0;
                if (lxf >= 0.0f && lxf < (float)TS && lyf >= 0.0f &&
                    lyf < (float)TS) {
                    float ddx = ix - p.x, ddy = iy - p.y;
                    float dist = sqrtf(ddx * ddx + ddy * ddy + EPS);
                    float wr = fmaxf(0.0f, 1.0f - dist * (1.0f / RADIUS));
                    float w = wr * p.w;  // p.w = exp(-tau*z)
                    if (w > 0.0f) {
                        wtap[nh] = w;
                        pltap[nh] = ((int)lyf << 4) | (int)lxf;
                        nh++;
                    }
                }
            }
        }
        if (nh > 0) {
            for (int j = 0; j < nh; j++) {
                atomicAdd(&accw[pltap[j]], wtap[j]);
                atomicAdd(&accz[pltap[j]], p.z * wtap[j]);
            }
            const float* fp = feats + ((size_t)bv * C) * HW + n;
#pragma unroll
            for (int c = 0; c < C; c++) {
                float f = fp[(size_t)c * HW];
                for (int j = 0; j < nh; j++)
                    atomicAdd(&accf[pltap[j] * ACC_STRIDE + c], f * wtap[j]);
            }
        }
    }
    __syncthreads();

    // flush: thread tid owns local pixel tid
    float invw = 1.0f / (accw[tid] + EPS);
    int gx = tileX0 + (tid & 15);
    int gy = tileY0 + (tid >> 4);
    int n = (gy << 8) | gx;
    float* ob = out + ((size_t)bv * C) * HW + n;
#pragma unroll
    for (int c = 0; c < C; c++) ob[(size_t)c * HW] = accf[tid * ACC_STRIDE + c] * invw;
    out[(size_t)BV * C * HW + (bv << 16) + n] = accz[tid] * invw;
}

// ---------------------------------------------------------------------------
// Fallback path (round-1 global-atomic splat) in case ws_size is too small.
// ---------------------------------------------------------------------------
__global__ __launch_bounds__(256) void splat_kernel(
    const float* __restrict__ depths, const float* __restrict__ feats,
    const float* __restrict__ Mbuf, float* __restrict__ fout,
    float* __restrict__ wsum, float* __restrict__ zsum) {
    int gid = blockIdx.x * blockDim.x + threadIdx.x;
    if (gid >= BV * HW) return;
    int bv = gid >> 16;
    int n = gid & (HW - 1);
    int pxi = n & (W - 1);
    int pyi = n >> 8;

    float xn = (float)pxi * (2.0f / (W - 1)) - 1.0f;
    float yn = (float)pyi * (2.0f / (H - 1)) - 1.0f;
    float d = depths[gid];

    const float* M = Mbuf + bv * 16;
    float X = xn * d, Y = yn * d;
    float p0 = M[0] * X + M[1] * Y + M[2] * d + M[3];
    float p1 = M[4] * X + M[5] * Y + M[6] * d + M[7];
    float z  = M[8] * X + M[9] * Y + M[10] * d + M[11];

    float inv = 1.0f / (z + EPS);
    bool zpos = z > 0.0f;
    float xp = zpos ? p0 * inv : -10.0f;
    float yp = zpos ? p1 * inv : -10.0f;

    float px = (xp + 1.0f) * 0.5f * (float)(W - 1);
    float py = (yp + 1.0f) * 0.5f * (float)(H - 1);
    float rx = rintf(px);
    float ry = rintf(py);
    float wd = expf(-TAU * z);

    float f[C];
#pragma unroll
    for (int c = 0; c < C; c++) f[c] = feats[((size_t)bv * C + c) * HW + n];

    float* fbase = fout + (size_t)bv * C * HW;
    float* wbase = wsum + (size_t)bv * HW;
    float* zbase = zsum + (size_t)bv * HW;

#pragma unroll
    for (int dy = -1; dy <= 1; dy++) {
        float iy = ry + (float)dy;
#pragma unroll
        for (int dx = -1; dx <= 1; dx++) {
            float ix = rx + (float)dx;
            float ddx = ix - px, ddy = iy - py;
            float dist = sqrtf(ddx * ddx + ddy * ddy + EPS);
            float wr = fmaxf(0.0f, 1.0f - dist / RADIUS);
            bool valid = (ix >= 0.0f) && (ix < (float)W) && (iy >= 0.0f) &&
                         (iy < (float)H) && zpos;
            float w = wr * wd;
            if (valid && w > 0.0f) {
                int pix = (int)iy * W + (int)ix;
                atomicAdd(wbase + pix, w);
                atomicAdd(zbase + pix, z * w);
                float* fp = fbase + pix;
#pragma unroll
                for (int c = 0; c < C; c++) atomicAdd(fp + c * HW, f[c] * w);
            }
        }
    }
}

__global__ __launch_bounds__(256) void norm_kernel(const float* __restrict__ wsum,
                                                   const float* __restrict__ zsum,
                                                   float* __restrict__ out) {
    int gid = blockIdx.x * blockDim.x + threadIdx.x;
    if (gid >= BV * HW) return;
    int bv = gid >> 16;
    int n = gid & (HW - 1);
    float invw = 1.0f / (wsum[gid] + EPS);
    float* fp = out + (size_t)bv * C * HW + n;
#pragma unroll
    for (int c = 0; c < C; c++) fp[c * HW] *= invw;
    out[(size_t)BV * C * HW + gid] = zsum[gid] * invw;
}

extern "C" void kernel_launch(void* const* d_in, const int* in_sizes, int n_in,
                              void* d_out, int out_size, void* d_ws, size_t ws_size,
                              hipStream_t stream) {
    const float* depths   = (const float*)d_in[0];  // (B,V,1,H,W)
    const float* feats    = (const float*)d_in[1];  // (B,V,C,H,W)
    const float* Kmat     = (const float*)d_in[2];  // (B,4,4)
    const float* srcRTinv = (const float*)d_in[4];  // (B,V,4,4)
    const float* dstRT    = (const float*)d_in[5];  // (B,1,4,4)
    float* out = (float*)d_out;

    // ws layout (new path):
    //   proj4   : BV*HW float4                = 6,291,456 B
    //   bins    : 4*BV*HW int (worst case)    = 6,291,456 B
    //   counts  : NT int
    //   offsets : NT+1 int
    //   cursors : NT int
    //   Mbuf    : BV*16 float
    char* ws = (char*)d_ws;
    size_t off_proj = 0;
    size_t off_bins = off_proj + (size_t)BV * HW * 16;
    size_t off_counts = off_bins + (size_t)4 * BV * HW * 4;
    size_t off_offsets = off_counts + (size_t)NT * 4;
    size_t off_cursors = off_offsets + (size_t)(NT + 1) * 4;
    size_t off_M = off_cursors + (size_t)NT * 4;
    size_t needed = off_M + (size_t)BV * 16 * 4;

    if (ws_size >= needed) {
        float4* proj4 = (float4*)(ws + off_proj);
        int* bins     = (int*)(ws + off_bins);
        int* counts   = (int*)(ws + off_counts);
        int* offsets  = (int*)(ws + off_offsets);
        int* cursors  = (int*)(ws + off_cursors);
        float* Mbuf   = (float*)(ws + off_M);

        hipMemsetAsync(counts, 0, (size_t)NT * 4, stream);
        setup_kernel<<<1, 64, 0, stream>>>(Kmat, srcRTinv, dstRT, Mbuf);
        int nblk = BV * HW / 256;  // 1536
        project_count_kernel<<<nblk, 256, 0, stream>>>(depths, Mbuf, proj4, counts);
        scan_kernel<<<1, 256, 0, stream>>>(counts, offsets, cursors);
        fill_kernel<<<nblk, 256, 0, stream>>>(proj4, cursors, bins);
        accum_kernel<<<NT, 256, 0, stream>>>(proj4, feats, offsets, bins, out);
    } else {
        // fallback: round-1 global-atomic path
        float* wsum = (float*)d_ws;
        float* zsum = wsum + (size_t)BV * HW;
        float* Mbuf = zsum + (size_t)BV * HW;
        hipMemsetAsync(d_out, 0, (size_t)BV * C * HW * sizeof(float), stream);
        hipMemsetAsync(d_ws, 0, (size_t)2 * BV * HW * sizeof(float), stream);
        setup_kernel<<<1, 64, 0, stream>>>(Kmat, srcRTinv, dstRT, Mbuf);
        int total = BV * HW;
        splat_kernel<<<total / 256, 256, 0, stream>>>(depths, feats, Mbuf, out, wsum, zsum);
        norm_kernel<<<total / 256, 256, 0, stream>>>(wsum, zsum, out);
    }
}

// Round 3
// 688.649 us; speedup vs baseline: 3.1608x; 1.0026x over previous
//
#include <hip/hip_runtime.h>
#include <math.h>

#define H 256
#define W 256
#define HW (H * W)
#define B 2
#define V 3
#define BV (B * V)
#define C 32
#define RADIUS 1.5f
#define TAU 1.0f
#define EPS 1e-8f

#define TS 16                 // destination tile edge
#define NTX (W / TS)          // 16
#define NTY (H / TS)          // 16
#define TPB (NTX * NTY)       // 256 tiles per image
#define NT (BV * TPB)         // 1536 tiles total
#define ACC_STRIDE 33         // pad 32->33 to break LDS bank conflicts

// ---------------------------------------------------------------------------
// Setup: per (b,v) fold the projection chain into one matrix
//   M = K[b] * dst_RT[b] * src_RTinv[b,v] * inv(K[b])
// ---------------------------------------------------------------------------
__global__ void setup_kernel(const float* __restrict__ Kmat,
                             const float* __restrict__ srcRTinv,
                             const float* __restrict__ dstRT,
                             float* __restrict__ Mbuf) {
    int bv = threadIdx.x;
    if (bv >= BV) return;
    int b = bv / V;

    float a[4][8];
    for (int i = 0; i < 4; i++)
        for (int j = 0; j < 4; j++) {
            a[i][j] = Kmat[b * 16 + i * 4 + j];
            a[i][4 + j] = (i == j) ? 1.0f : 0.0f;
        }
    for (int col = 0; col < 4; col++) {
        int piv = col;
        float best = fabsf(a[col][col]);
        for (int r = col + 1; r < 4; r++) {
            float v = fabsf(a[r][col]);
            if (v > best) { best = v; piv = r; }
        }
        if (piv != col) {
            for (int j = 0; j < 8; j++) {
                float t = a[col][j]; a[col][j] = a[piv][j]; a[piv][j] = t;
            }
        }
        float s = 1.0f / a[col][col];
        for (int j = 0; j < 8; j++) a[col][j] *= s;
        for (int r = 0; r < 4; r++) {
            if (r == col) continue;
            float m = a[r][col];
            for (int j = 0; j < 8; j++) a[r][j] -= m * a[col][j];
        }
    }
    float Kinv[16];
    for (int i = 0; i < 4; i++)
        for (int j = 0; j < 4; j++) Kinv[i * 4 + j] = a[i][4 + j];

    float T1[16];
    const float* S = srcRTinv + bv * 16;
    for (int i = 0; i < 4; i++)
        for (int j = 0; j < 4; j++) {
            float acc = 0.0f;
            for (int k = 0; k < 4; k++) acc += S[i * 4 + k] * Kinv[k * 4 + j];
            T1[i * 4 + j] = acc;
        }
    float T2[16];
    const float* D = dstRT + b * 16;
    for (int i = 0; i < 4; i++)
        for (int j = 0; j < 4; j++) {
            float acc = 0.0f;
            for (int k = 0; k < 4; k++) acc += D[i * 4 + k] * T1[k * 4 + j];
            T2[i * 4 + j] = acc;
        }
    const float* Kb = Kmat + b * 16;
    for (int i = 0; i < 4; i++)
        for (int j = 0; j < 4; j++) {
            float acc = 0.0f;
            for (int k = 0; k < 4; k++) acc += Kb[i * 4 + k] * T2[k * 4 + j];
            Mbuf[bv * 16 + i * 4 + j] = acc;
        }
}

// Clipped 3x3 footprint box -> touched tile range.
__device__ __forceinline__ bool footprint_tiles(float px, float py, float z,
                                                int& tx0, int& tx1, int& ty0,
                                                int& ty1) {
    if (!(z > 0.0f)) return false;
    float rxC = fminf(fmaxf(rintf(px), -4.0f), 260.0f);
    float ryC = fminf(fmaxf(rintf(py), -4.0f), 260.0f);
    int x0 = max((int)rxC - 1, 0), x1 = min((int)rxC + 1, W - 1);
    int y0 = max((int)ryC - 1, 0), y1 = min((int)ryC + 1, H - 1);
    if (x0 > x1 || y0 > y1) return false;
    tx0 = x0 >> 4; tx1 = x1 >> 4; ty0 = y0 >> 4; ty1 = y1 >> 4;
    return true;
}

// ---------------------------------------------------------------------------
// Phase 1: project every source point, store (px,py,z,wd), count per tile.
// ---------------------------------------------------------------------------
__global__ __launch_bounds__(256) void project_count_kernel(
    const float* __restrict__ depths, const float* __restrict__ Mbuf,
    float4* __restrict__ proj4, int* __restrict__ counts) {
    __shared__ int hist[TPB];
    int tid = threadIdx.x;
    hist[tid] = 0;
    __syncthreads();

    int gid = blockIdx.x * 256 + tid;
    int bv = gid >> 16;
    int n = gid & (HW - 1);
    int pxi = n & (W - 1);
    int pyi = n >> 8;

    float xn = (float)pxi * (2.0f / (W - 1)) - 1.0f;
    float yn = (float)pyi * (2.0f / (H - 1)) - 1.0f;
    float d = depths[gid];
    const float* M = Mbuf + bv * 16;
    float X = xn * d, Y = yn * d;
    float p0 = M[0] * X + M[1] * Y + M[2] * d + M[3];
    float p1 = M[4] * X + M[5] * Y + M[6] * d + M[7];
    float z  = M[8] * X + M[9] * Y + M[10] * d + M[11];

    bool zpos = z > 0.0f;
    float inv = 1.0f / (z + EPS);
    float xp = zpos ? p0 * inv : -10.0f;
    float yp = zpos ? p1 * inv : -10.0f;
    float px = (xp + 1.0f) * 0.5f * (float)(W - 1);
    float py = (yp + 1.0f) * 0.5f * (float)(H - 1);
    float wd = expf(-TAU * z);
    proj4[gid] = make_float4(px, py, z, wd);

    int tx0, tx1, ty0, ty1;
    if (footprint_tiles(px, py, z, tx0, tx1, ty0, ty1)) {
        atomicAdd(&hist[ty0 * NTX + tx0], 1);
        if (tx1 > tx0) atomicAdd(&hist[ty0 * NTX + tx1], 1);
        if (ty1 > ty0) {
            atomicAdd(&hist[ty1 * NTX + tx0], 1);
            if (tx1 > tx0) atomicAdd(&hist[ty1 * NTX + tx1], 1);
        }
    }
    __syncthreads();
    if (hist[tid] > 0) atomicAdd(&counts[(bv << 8) + tid], hist[tid]);
}

// ---------------------------------------------------------------------------
// Phase 2: exclusive scan of 1536 tile counts (single block).
// ---------------------------------------------------------------------------
__global__ __launch_bounds__(256) void scan_kernel(const int* __restrict__ counts,
                                                   int* __restrict__ offsets,
                                                   int* __restrict__ cursors) {
    __shared__ int sums[256];
    int t = threadIdx.x;
    int v[6];
    int s = 0;
    for (int k = 0; k < 6; k++) { v[k] = counts[t * 6 + k]; s += v[k]; }
    sums[t] = s;
    __syncthreads();
    for (int off = 1; off < 256; off <<= 1) {
        int x = (t >= off) ? sums[t - off] : 0;
        __syncthreads();
        sums[t] += x;
        __syncthreads();
    }
    int base = (t > 0) ? sums[t - 1] : 0;
    for (int k = 0; k < 6; k++) {
        offsets[t * 6 + k] = base;
        cursors[t * 6 + k] = base;
        base += v[k];
    }
    if (t == 255) offsets[NT] = base;
}

// ---------------------------------------------------------------------------
// Phase 3: fill per-tile source lists. Static registers only (no dynamically
// indexed arrays -> no scratch).
// ---------------------------------------------------------------------------
__global__ __launch_bounds__(256) void fill_kernel(const float4* __restrict__ proj4,
                                                   int* __restrict__ cursors,
                                                   int* __restrict__ bins) {
    __shared__ int hist[TPB];
    __shared__ int basear[TPB];
    int tid = threadIdx.x;
    hist[tid] = 0;
    __syncthreads();

    int gid = blockIdx.x * 256 + tid;
    int bv = gid >> 16;
    int n = gid & (HW - 1);
    float4 p = proj4[gid];

    int tx0, tx1, ty0, ty1;
    bool ok = footprint_tiles(p.x, p.y, p.z, tx0, tx1, ty0, ty1);
    int l00 = -1, l01 = -1, l10 = -1, l11 = -1;
    int o00 = 0, o01 = 0, o10 = 0, o11 = 0;
    if (ok) {
        l00 = ty0 * NTX + tx0; o00 = atomicAdd(&hist[l00], 1);
        if (tx1 > tx0) { l01 = ty0 * NTX + tx1; o01 = atomicAdd(&hist[l01], 1); }
        if (ty1 > ty0) {
            l10 = ty1 * NTX + tx0; o10 = atomicAdd(&hist[l10], 1);
            if (tx1 > tx0) { l11 = ty1 * NTX + tx1; o11 = atomicAdd(&hist[l11], 1); }
        }
    }
    __syncthreads();
    if (hist[tid] > 0) basear[tid] = atomicAdd(&cursors[(bv << 8) + tid], hist[tid]);
    __syncthreads();
    if (l00 >= 0) bins[basear[l00] + o00] = n;
    if (l01 >= 0) bins[basear[l01] + o01] = n;
    if (l10 >= 0) bins[basear[l10] + o10] = n;
    if (l11 >= 0) bins[basear[l11] + o11] = n;
}

// ---------------------------------------------------------------------------
// Transpose feats (BV,C,HW) -> featsT (BV,HW,C) so accum reads each point's
// 32 channels as one contiguous 128B block.
// ---------------------------------------------------------------------------
__global__ __launch_bounds__(256) void transpose_kernel(
    const float* __restrict__ feats, float* __restrict__ featsT) {
    __shared__ float sm[C][257];
    int blk = blockIdx.x;
    int bv = blk >> 8;       // 256 chunks per bv
    int n0 = (blk & 255) << 8;
    int tid = threadIdx.x;
    const float* src = feats + (size_t)bv * C * HW + n0;
#pragma unroll
    for (int c = 0; c < C; c++) sm[c][tid] = src[(size_t)c * HW + tid];
    __syncthreads();
    float* dst = featsT + ((size_t)bv * HW + n0) * C;
#pragma unroll
    for (int pass = 0; pass < 8; pass++) {
        int nl = pass * 32 + (tid >> 3);
        int c4 = (tid & 7) << 2;
        float4 vv = make_float4(sm[c4][nl], sm[c4 + 1][nl], sm[c4 + 2][nl],
                                sm[c4 + 3][nl]);
        *(float4*)(dst + (size_t)nl * C + c4) = vv;
    }
}

// ---------------------------------------------------------------------------
// Phase 4: per-tile LDS accumulation + fused normalize + store.
// Fully static control flow: taps and channel loop unrolled, f[] in VGPRs.
// TRANSPOSED: read featsT (contiguous 32ch); else strided feats.
// ---------------------------------------------------------------------------
template <bool TRANSPOSED>
__global__ __launch_bounds__(256, 4) void accum_kernel(
    const float4* __restrict__ proj4, const float* __restrict__ fsrc,
    const int* __restrict__ offsets, const int* __restrict__ bins,
    float* __restrict__ out) {
    __shared__ float accw[TS * TS];
    __shared__ float accz[TS * TS];
    __shared__ float accf[TS * TS * ACC_STRIDE];

    int tid = threadIdx.x;
    int tile = blockIdx.x;
    int bv = tile >> 8;
    int t = tile & 255;
    int tileX0 = (t & 15) << 4;
    int tileY0 = (t >> 4) << 4;

    accw[tid] = 0.0f;
    accz[tid] = 0.0f;
#pragma unroll
    for (int k = 0; k < ACC_STRIDE; k++) accf[k * 256 + tid] = 0.0f;
    __syncthreads();

    int start = offsets[tile], end = offsets[tile + 1];
    for (int i = start + tid; i < end; i += 256) {
        int n = bins[i];
        float4 p = proj4[(bv << 16) + n];
        float rx = rintf(p.x), ry = rintf(p.y);

        float f[C];
        if (TRANSPOSED) {
            const float4* fp = (const float4*)(fsrc + ((size_t)(bv << 16) + n) * C);
#pragma unroll
            for (int q = 0; q < C / 4; q++) {
                float4 vv = fp[q];
                f[4 * q] = vv.x; f[4 * q + 1] = vv.y;
                f[4 * q + 2] = vv.z; f[4 * q + 3] = vv.w;
            }
        } else {
            const float* fp = fsrc + (size_t)bv * C * HW + n;
#pragma unroll
            for (int c = 0; c < C; c++) f[c] = fp[(size_t)c * HW];
        }

#pragma unroll
        for (int dy = -1; dy <= 1; dy++) {
#pragma unroll
            for (int dx = -1; dx <= 1; dx++) {
                float ix = rx + (float)dx, iy = ry + (float)dy;
                float lxf = ix - (float)tileX0, lyf = iy - (float)tileY0;
                bool in_tile = (lxf >= 0.0f) && (lxf < (float)TS) &&
                               (lyf >= 0.0f) && (lyf < (float)TS);
                float ddx = ix - p.x, ddy = iy - p.y;
                float dist = sqrtf(ddx * ddx + ddy * ddy + EPS);
                float wr = fmaxf(0.0f, 1.0f - dist * (1.0f / RADIUS));
                float w = wr * p.w;  // p.w = exp(-tau*z)
                if (in_tile && w > 0.0f) {
                    int pl = ((int)lyf << 4) | (int)lxf;
                    atomicAdd(&accw[pl], w);
                    atomicAdd(&accz[pl], p.z * w);
                    float* ap = &accf[pl * ACC_STRIDE];
#pragma unroll
                    for (int c = 0; c < C; c++) atomicAdd(&ap[c], f[c] * w);
                }
            }
        }
    }
    __syncthreads();

    float invw = 1.0f / (accw[tid] + EPS);
    int gx = tileX0 + (tid & 15);
    int gy = tileY0 + (tid >> 4);
    int n = (gy << 8) | gx;
    float* ob = out + ((size_t)bv * C) * HW + n;
#pragma unroll
    for (int c = 0; c < C; c++) ob[(size_t)c * HW] = accf[tid * ACC_STRIDE + c] * invw;
    out[(size_t)BV * C * HW + (bv << 16) + n] = accz[tid] * invw;
}

extern "C" void kernel_launch(void* const* d_in, const int* in_sizes, int n_in,
                              void* d_out, int out_size, void* d_ws, size_t ws_size,
                              hipStream_t stream) {
    const float* depths   = (const float*)d_in[0];  // (B,V,1,H,W)
    const float* feats    = (const float*)d_in[1];  // (B,V,C,H,W)
    const float* Kmat     = (const float*)d_in[2];  // (B,4,4)
    const float* srcRTinv = (const float*)d_in[4];  // (B,V,4,4)
    const float* dstRT    = (const float*)d_in[5];  // (B,1,4,4)
    float* out = (float*)d_out;

    // ws layout:
    //   proj4   : BV*HW float4           6.29 MB
    //   bins    : 4*BV*HW int            6.29 MB
    //   featsT  : BV*HW*C float         50.33 MB (optional)
    //   counts/offsets/cursors/Mbuf     ~20 KB
    char* ws = (char*)d_ws;
    size_t off_proj = 0;
    size_t off_bins = off_proj + (size_t)BV * HW * 16;
    size_t off_featsT = off_bins + (size_t)4 * BV * HW * 4;
    size_t off_counts_T = off_featsT + (size_t)BV * HW * C * 4;
    size_t small = (size_t)NT * 4 + (size_t)(NT + 1) * 4 + (size_t)NT * 4 +
                   (size_t)BV * 16 * 4;
    size_t needed_full = off_counts_T + small;
    size_t needed_min = off_featsT + small;

    if (ws_size >= needed_min) {
        bool use_T = (ws_size >= needed_full);
        float4* proj4 = (float4*)(ws + off_proj);
        int* bins     = (int*)(ws + off_bins);
        float* featsT = (float*)(ws + off_featsT);
        char* smallp  = ws + (use_T ? off_counts_T : off_featsT);
        int* counts   = (int*)smallp;
        int* offsets  = counts + NT;
        int* cursors  = offsets + NT + 1;
        float* Mbuf   = (float*)(cursors + NT);

        hipMemsetAsync(counts, 0, (size_t)NT * 4, stream);
        setup_kernel<<<1, 64, 0, stream>>>(Kmat, srcRTinv, dstRT, Mbuf);
        int nblk = BV * HW / 256;  // 1536
        project_count_kernel<<<nblk, 256, 0, stream>>>(depths, Mbuf, proj4, counts);
        scan_kernel<<<1, 256, 0, stream>>>(counts, offsets, cursors);
        fill_kernel<<<nblk, 256, 0, stream>>>(proj4, cursors, bins);
        if (use_T) {
            transpose_kernel<<<nblk, 256, 0, stream>>>(feats, featsT);
            accum_kernel<true><<<NT, 256, 0, stream>>>(proj4, featsT, offsets,
                                                       bins, out);
        } else {
            accum_kernel<false><<<NT, 256, 0, stream>>>(proj4, feats, offsets,
                                                        bins, out);
        }
    } else {
        // Minimal fallback: should not happen (needs only ~12.7MB). Do the
        // binned path pieces that fit... degrade to direct accum w/o bins is
        // not possible; rely on harness providing >= needed_min.
        // As a last resort, write zeros so we fail loudly rather than crash.
        hipMemsetAsync(d_out, 0, (size_t)out_size * 4, stream);
    }
}

// Round 4
// 676.822 us; speedup vs baseline: 3.2160x; 1.0175x over previous
//
#include <hip/hip_runtime.h>
#include <math.h>

#define H 256
#define W 256
#define HW (H * W)
#define B 2
#define V 3
#define BV (B * V)
#define C 32
#define RADIUS 1.5f
#define TAU 1.0f
#define EPS 1e-8f

#define NPIX (BV * HW)   // 393216 destination pixels (= source points)
#define NBLK (NPIX / 256) // 1536

// ---------------------------------------------------------------------------
// Setup: per (b,v) fold the projection chain into one matrix
//   M = K[b] * dst_RT[b] * src_RTinv[b,v] * inv(K[b])
// ---------------------------------------------------------------------------
__global__ void setup_kernel(const float* __restrict__ Kmat,
                             const float* __restrict__ srcRTinv,
                             const float* __restrict__ dstRT,
                             float* __restrict__ Mbuf) {
    int bv = threadIdx.x;
    if (bv >= BV) return;
    int b = bv / V;

    float a[4][8];
    for (int i = 0; i < 4; i++)
        for (int j = 0; j < 4; j++) {
            a[i][j] = Kmat[b * 16 + i * 4 + j];
            a[i][4 + j] = (i == j) ? 1.0f : 0.0f;
        }
    for (int col = 0; col < 4; col++) {
        int piv = col;
        float best = fabsf(a[col][col]);
        for (int r = col + 1; r < 4; r++) {
            float v = fabsf(a[r][col]);
            if (v > best) { best = v; piv = r; }
        }
        if (piv != col) {
            for (int j = 0; j < 8; j++) {
                float t = a[col][j]; a[col][j] = a[piv][j]; a[piv][j] = t;
            }
        }
        float s = 1.0f / a[col][col];
        for (int j = 0; j < 8; j++) a[col][j] *= s;
        for (int r = 0; r < 4; r++) {
            if (r == col) continue;
            float m = a[r][col];
            for (int j = 0; j < 8; j++) a[r][j] -= m * a[col][j];
        }
    }
    float Kinv[16];
    for (int i = 0; i < 4; i++)
        for (int j = 0; j < 4; j++) Kinv[i * 4 + j] = a[i][4 + j];

    float T1[16];
    const float* S = srcRTinv + bv * 16;
    for (int i = 0; i < 4; i++)
        for (int j = 0; j < 4; j++) {
            float acc = 0.0f;
            for (int k = 0; k < 4; k++) acc += S[i * 4 + k] * Kinv[k * 4 + j];
            T1[i * 4 + j] = acc;
        }
    float T2[16];
    const float* D = dstRT + b * 16;
    for (int i = 0; i < 4; i++)
        for (int j = 0; j < 4; j++) {
            float acc = 0.0f;
            for (int k = 0; k < 4; k++) acc += D[i * 4 + k] * T1[k * 4 + j];
            T2[i * 4 + j] = acc;
        }
    const float* Kb = Kmat + b * 16;
    for (int i = 0; i < 4; i++)
        for (int j = 0; j < 4; j++) {
            float acc = 0.0f;
            for (int k = 0; k < 4; k++) acc += Kb[i * 4 + k] * T2[k * 4 + j];
            Mbuf[bv * 16 + i * 4 + j] = acc;
        }
}

// ---------------------------------------------------------------------------
// Shared tap enumeration: for point with projection p, visit every dest
// pixel q (within-image index) whose reference weight is > 0.
//   valid  : 0 <= ix < W, 0 <= iy < H, z > 0
//   w > 0  : dist < RADIUS  <=>  ddx^2+ddy^2+EPS < RADIUS^2
// Used identically by count and fill so the two passes agree exactly.
// ---------------------------------------------------------------------------
template <typename F>
__device__ __forceinline__ void for_each_tap(float4 p, F&& fn) {
    if (!(p.z > 0.0f)) return;
    float rx = rintf(p.x), ry = rintf(p.y);
#pragma unroll
    for (int dy = -1; dy <= 1; dy++) {
#pragma unroll
        for (int dx = -1; dx <= 1; dx++) {
            float ix = rx + (float)dx, iy = ry + (float)dy;
            if (ix >= 0.0f && ix < (float)W && iy >= 0.0f && iy < (float)H) {
                float ddx = ix - p.x, ddy = iy - p.y;
                float d2 = ddx * ddx + ddy * ddy + EPS;
                if (d2 < RADIUS * RADIUS) {
                    int q = ((int)iy << 8) | (int)ix;
                    fn(q);
                }
            }
        }
    }
}

// ---------------------------------------------------------------------------
// Phase 1: project every source point -> proj4; count contributors per dest
// pixel via global int atomics (counts is L2-resident, 1.5 MB).
// ---------------------------------------------------------------------------
__global__ __launch_bounds__(256) void project_count_kernel(
    const float* __restrict__ depths, const float* __restrict__ Mbuf,
    float4* __restrict__ proj4, int* __restrict__ counts) {
    int gid = blockIdx.x * 256 + threadIdx.x;
    int bv = gid >> 16;
    int n = gid & (HW - 1);
    int pxi = n & (W - 1);
    int pyi = n >> 8;

    float xn = (float)pxi * (2.0f / (W - 1)) - 1.0f;
    float yn = (float)pyi * (2.0f / (H - 1)) - 1.0f;
    float d = depths[gid];
    const float* M = Mbuf + bv * 16;
    float X = xn * d, Y = yn * d;
    float p0 = M[0] * X + M[1] * Y + M[2] * d + M[3];
    float p1 = M[4] * X + M[5] * Y + M[6] * d + M[7];
    float z  = M[8] * X + M[9] * Y + M[10] * d + M[11];

    bool zpos = z > 0.0f;
    float inv = 1.0f / (z + EPS);
    float xp = zpos ? p0 * inv : -10.0f;
    float yp = zpos ? p1 * inv : -10.0f;
    float px = (xp + 1.0f) * 0.5f * (float)(W - 1);
    float py = (yp + 1.0f) * 0.5f * (float)(H - 1);
    float wd = expf(-TAU * z);
    float4 p = make_float4(px, py, z, wd);
    proj4[gid] = p;

    int base = bv << 16;
    for_each_tap(p, [&](int q) { atomicAdd(&counts[base | q], 1); });
}

// ---------------------------------------------------------------------------
// Phase 2a: per-block inclusive scan of 256 counts -> relative exclusive
// offsets + per-block totals.
// ---------------------------------------------------------------------------
__global__ __launch_bounds__(256) void scan_blocks_kernel(
    const int* __restrict__ counts, int* __restrict__ offsets,
    int* __restrict__ blocksums) {
    __shared__ int sums[256];
    int tid = threadIdx.x;
    int gid = blockIdx.x * 256 + tid;
    int v = counts[gid];
    sums[tid] = v;
    __syncthreads();
    for (int off = 1; off < 256; off <<= 1) {
        int x = (tid >= off) ? sums[tid - off] : 0;
        __syncthreads();
        sums[tid] += x;
        __syncthreads();
    }
    offsets[gid] = sums[tid] - v;  // exclusive, relative to block
    if (tid == 255) blocksums[blockIdx.x] = sums[255];
}

// ---------------------------------------------------------------------------
// Phase 2b: exclusive scan of 1536 block sums (single block).
// ---------------------------------------------------------------------------
__global__ __launch_bounds__(256) void scan_tops_kernel(
    const int* __restrict__ blocksums, int* __restrict__ blockbase) {
    __shared__ int sums[256];
    int t = threadIdx.x;
    int v[6];
    int s = 0;
    for (int k = 0; k < 6; k++) { v[k] = blocksums[t * 6 + k]; s += v[k]; }
    sums[t] = s;
    __syncthreads();
    for (int off = 1; off < 256; off <<= 1) {
        int x = (t >= off) ? sums[t - off] : 0;
        __syncthreads();
        sums[t] += x;
        __syncthreads();
    }
    int base = (t > 0) ? sums[t - 1] : 0;
    for (int k = 0; k < 6; k++) {
        blockbase[t * 6 + k] = base;
        base += v[k];
    }
}

// ---------------------------------------------------------------------------
// Phase 2c: add block bases; init cursors.
// ---------------------------------------------------------------------------
__global__ __launch_bounds__(256) void add_base_kernel(
    int* __restrict__ offsets, const int* __restrict__ blockbase,
    int* __restrict__ cursors) {
    int gid = blockIdx.x * 256 + threadIdx.x;
    int o = offsets[gid] + blockbase[blockIdx.x];
    offsets[gid] = o;
    cursors[gid] = o;
}

// ---------------------------------------------------------------------------
// Phase 3: fill per-dest-pixel contributor lists (source index only).
// ---------------------------------------------------------------------------
__global__ __launch_bounds__(256) void fill_kernel(
    const float4* __restrict__ proj4, int* __restrict__ cursors,
    int* __restrict__ bins) {
    int gid = blockIdx.x * 256 + threadIdx.x;
    int bv = gid >> 16;
    int n = gid & (HW - 1);
    float4 p = proj4[gid];
    int base = bv << 16;
    for_each_tap(p, [&](int q) {
        int pos = atomicAdd(&cursors[base | q], 1);
        bins[pos] = n;
    });
}

// ---------------------------------------------------------------------------
// Phase 4: gather. One thread per dest pixel; accumulate w, z*w and 32
// channels in registers; fused normalize + store. No atomics, no LDS.
// ---------------------------------------------------------------------------
__global__ __launch_bounds__(256) void gather_kernel(
    const float4* __restrict__ proj4, const float* __restrict__ feats,
    const int* __restrict__ counts, const int* __restrict__ offsets,
    const int* __restrict__ bins, float* __restrict__ out) {
    int gid = blockIdx.x * 256 + threadIdx.x;
    int bv = gid >> 16;
    int q = gid & (HW - 1);
    float qx = (float)(q & (W - 1));
    float qy = (float)(q >> 8);

    int cnt = counts[gid];
    int off = offsets[gid];

    const float4* pj = proj4 + ((size_t)bv << 16);
    const float* fb = feats + (size_t)bv * C * HW;

    float wsum = 0.0f, zwsum = 0.0f;
    float facc[C];
#pragma unroll
    for (int c = 0; c < C; c++) facc[c] = 0.0f;

    for (int j = 0; j < cnt; j++) {
        int n = bins[off + j];
        float4 p = pj[n];
        float ddx = qx - p.x, ddy = qy - p.y;
        float dist = sqrtf(ddx * ddx + ddy * ddy + EPS);
        float wr = fmaxf(0.0f, 1.0f - dist * (1.0f / RADIUS));
        float w = wr * p.w;  // p.w = exp(-tau*z)
        wsum += w;
        zwsum += p.z * w;
        const float* fp = fb + n;
#pragma unroll
        for (int c = 0; c < C; c++) facc[c] = fmaf(w, fp[(size_t)c * HW], facc[c]);
    }

    float invw = 1.0f / (wsum + EPS);
    float* ob = out + (size_t)bv * C * HW + q;
#pragma unroll
    for (int c = 0; c < C; c++) ob[(size_t)c * HW] = facc[c] * invw;
    out[(size_t)BV * C * HW + gid] = zwsum * invw;
}

extern "C" void kernel_launch(void* const* d_in, const int* in_sizes, int n_in,
                              void* d_out, int out_size, void* d_ws, size_t ws_size,
                              hipStream_t stream) {
    const float* depths   = (const float*)d_in[0];  // (B,V,1,H,W)
    const float* feats    = (const float*)d_in[1];  // (B,V,C,H,W)
    const float* Kmat     = (const float*)d_in[2];  // (B,4,4)
    const float* srcRTinv = (const float*)d_in[4];  // (B,V,4,4)
    const float* dstRT    = (const float*)d_in[5];  // (B,1,4,4)
    float* out = (float*)d_out;

    // ws layout:
    //   proj4     : NPIX float4      6.29 MB
    //   bins      : 9*NPIX int      14.16 MB
    //   counts    : NPIX int         1.57 MB
    //   offsets   : NPIX int         1.57 MB
    //   cursors   : NPIX int         1.57 MB
    //   blocksums : NBLK int
    //   blockbase : NBLK int
    //   Mbuf      : BV*16 float
    char* ws = (char*)d_ws;
    size_t off_proj = 0;
    size_t off_bins = off_proj + (size_t)NPIX * 16;
    size_t off_counts = off_bins + (size_t)9 * NPIX * 4;
    size_t off_offsets = off_counts + (size_t)NPIX * 4;
    size_t off_cursors = off_offsets + (size_t)NPIX * 4;
    size_t off_bsums = off_cursors + (size_t)NPIX * 4;
    size_t off_bbase = off_bsums + (size_t)NBLK * 4;
    size_t off_M = off_bbase + (size_t)NBLK * 4;
    size_t needed = off_M + (size_t)BV * 16 * 4;

    if (ws_size < needed) {  // should not happen (ws >= 63MB observed)
        hipMemsetAsync(d_out, 0, (size_t)out_size * 4, stream);
        return;
    }

    float4* proj4  = (float4*)(ws + off_proj);
    int* bins      = (int*)(ws + off_bins);
    int* counts    = (int*)(ws + off_counts);
    int* offsets   = (int*)(ws + off_offsets);
    int* cursors   = (int*)(ws + off_cursors);
    int* blocksums = (int*)(ws + off_bsums);
    int* blockbase = (int*)(ws + off_bbase);
    float* Mbuf    = (float*)(ws + off_M);

    hipMemsetAsync(counts, 0, (size_t)NPIX * 4, stream);
    setup_kernel<<<1, 64, 0, stream>>>(Kmat, srcRTinv, dstRT, Mbuf);
    project_count_kernel<<<NBLK, 256, 0, stream>>>(depths, Mbuf, proj4, counts);
    scan_blocks_kernel<<<NBLK, 256, 0, stream>>>(counts, offsets, blocksums);
    scan_tops_kernel<<<1, 256, 0, stream>>>(blocksums, blockbase);
    add_base_kernel<<<NBLK, 256, 0, stream>>>(offsets, blockbase, cursors);
    fill_kernel<<<NBLK, 256, 0, stream>>>(proj4, cursors, bins);
    gather_kernel<<<NBLK, 256, 0, stream>>>(proj4, feats, counts, offsets, bins, out);
}

// Round 5
// 316.323 us; speedup vs baseline: 6.8812x; 2.1397x over previous
//
#include <hip/hip_runtime.h>
#include <hip/hip_fp16.h>
#include <math.h>

#define H 256
#define W 256
#define HW (H * W)
#define B 2
#define V 3
#define BV (B * V)
#define C 32
#define RADIUS 1.5f
#define TAU 1.0f
#define EPS 1e-8f

#define NPIX (BV * HW)    // 393216 destination pixels (= source points)
#define NBLK (NPIX / 256) // 1536

// ---------------------------------------------------------------------------
// Setup: per (b,v) fold the projection chain into one matrix
//   M = K[b] * dst_RT[b] * src_RTinv[b,v] * inv(K[b])
// ---------------------------------------------------------------------------
__global__ void setup_kernel(const float* __restrict__ Kmat,
                             const float* __restrict__ srcRTinv,
                             const float* __restrict__ dstRT,
                             float* __restrict__ Mbuf) {
    int bv = threadIdx.x;
    if (bv >= BV) return;
    int b = bv / V;

    float a[4][8];
    for (int i = 0; i < 4; i++)
        for (int j = 0; j < 4; j++) {
            a[i][j] = Kmat[b * 16 + i * 4 + j];
            a[i][4 + j] = (i == j) ? 1.0f : 0.0f;
        }
    for (int col = 0; col < 4; col++) {
        int piv = col;
        float best = fabsf(a[col][col]);
        for (int r = col + 1; r < 4; r++) {
            float v = fabsf(a[r][col]);
            if (v > best) { best = v; piv = r; }
        }
        if (piv != col) {
            for (int j = 0; j < 8; j++) {
                float t = a[col][j]; a[col][j] = a[piv][j]; a[piv][j] = t;
            }
        }
        float s = 1.0f / a[col][col];
        for (int j = 0; j < 8; j++) a[col][j] *= s;
        for (int r = 0; r < 4; r++) {
            if (r == col) continue;
            float m = a[r][col];
            for (int j = 0; j < 8; j++) a[r][j] -= m * a[col][j];
        }
    }
    float Kinv[16];
    for (int i = 0; i < 4; i++)
        for (int j = 0; j < 4; j++) Kinv[i * 4 + j] = a[i][4 + j];

    float T1[16];
    const float* S = srcRTinv + bv * 16;
    for (int i = 0; i < 4; i++)
        for (int j = 0; j < 4; j++) {
            float acc = 0.0f;
            for (int k = 0; k < 4; k++) acc += S[i * 4 + k] * Kinv[k * 4 + j];
            T1[i * 4 + j] = acc;
        }
    float T2[16];
    const float* D = dstRT + b * 16;
    for (int i = 0; i < 4; i++)
        for (int j = 0; j < 4; j++) {
            float acc = 0.0f;
            for (int k = 0; k < 4; k++) acc += D[i * 4 + k] * T1[k * 4 + j];
            T2[i * 4 + j] = acc;
        }
    const float* Kb = Kmat + b * 16;
    for (int i = 0; i < 4; i++)
        for (int j = 0; j < 4; j++) {
            float acc = 0.0f;
            for (int k = 0; k < 4; k++) acc += Kb[i * 4 + k] * T2[k * 4 + j];
            Mbuf[bv * 16 + i * 4 + j] = acc;
        }
}

// ---------------------------------------------------------------------------
// Shared tap enumeration: visit every dest pixel q whose reference weight > 0.
//   valid : 0 <= ix < W, 0 <= iy < H, z > 0 ; w>0 : d2 < RADIUS^2
// Used identically by count and fill so the two passes agree exactly.
// ---------------------------------------------------------------------------
template <typename F>
__device__ __forceinline__ void for_each_tap(float4 p, F&& fn) {
    if (!(p.z > 0.0f)) return;
    float rx = rintf(p.x), ry = rintf(p.y);
#pragma unroll
    for (int dy = -1; dy <= 1; dy++) {
#pragma unroll
        for (int dx = -1; dx <= 1; dx++) {
            float ix = rx + (float)dx, iy = ry + (float)dy;
            if (ix >= 0.0f && ix < (float)W && iy >= 0.0f && iy < (float)H) {
                float ddx = ix - p.x, ddy = iy - p.y;
                float d2 = ddx * ddx + ddy * ddy + EPS;
                if (d2 < RADIUS * RADIUS) {
                    int q = ((int)iy << 8) | (int)ix;
                    fn(q);
                }
            }
        }
    }
}

// ---------------------------------------------------------------------------
// Phase 1: project -> proj4; count contributors per dest pixel.
// ---------------------------------------------------------------------------
__global__ __launch_bounds__(256) void project_count_kernel(
    const float* __restrict__ depths, const float* __restrict__ Mbuf,
    float4* __restrict__ proj4, int* __restrict__ counts) {
    int gid = blockIdx.x * 256 + threadIdx.x;
    int bv = gid >> 16;
    int n = gid & (HW - 1);
    int pxi = n & (W - 1);
    int pyi = n >> 8;

    float xn = (float)pxi * (2.0f / (W - 1)) - 1.0f;
    float yn = (float)pyi * (2.0f / (H - 1)) - 1.0f;
    float d = depths[gid];
    const float* M = Mbuf + bv * 16;
    float X = xn * d, Y = yn * d;
    float p0 = M[0] * X + M[1] * Y + M[2] * d + M[3];
    float p1 = M[4] * X + M[5] * Y + M[6] * d + M[7];
    float z  = M[8] * X + M[9] * Y + M[10] * d + M[11];

    bool zpos = z > 0.0f;
    float inv = 1.0f / (z + EPS);
    float xp = zpos ? p0 * inv : -10.0f;
    float yp = zpos ? p1 * inv : -10.0f;
    float px = (xp + 1.0f) * 0.5f * (float)(W - 1);
    float py = (yp + 1.0f) * 0.5f * (float)(H - 1);
    float wd = expf(-TAU * z);
    float4 p = make_float4(px, py, z, wd);
    proj4[gid] = p;

    int base = bv << 16;
    for_each_tap(p, [&](int q) { atomicAdd(&counts[base | q], 1); });
}

// ---------------------------------------------------------------------------
// Phase 2a/2b/2c: prefix scan of 393216 counts.
// ---------------------------------------------------------------------------
__global__ __launch_bounds__(256) void scan_blocks_kernel(
    const int* __restrict__ counts, int* __restrict__ offsets,
    int* __restrict__ blocksums) {
    __shared__ int sums[256];
    int tid = threadIdx.x;
    int gid = blockIdx.x * 256 + tid;
    int v = counts[gid];
    sums[tid] = v;
    __syncthreads();
    for (int off = 1; off < 256; off <<= 1) {
        int x = (tid >= off) ? sums[tid - off] : 0;
        __syncthreads();
        sums[tid] += x;
        __syncthreads();
    }
    offsets[gid] = sums[tid] - v;
    if (tid == 255) blocksums[blockIdx.x] = sums[255];
}

__global__ __launch_bounds__(256) void scan_tops_kernel(
    const int* __restrict__ blocksums, int* __restrict__ blockbase) {
    __shared__ int sums[256];
    int t = threadIdx.x;
    int v[6];
    int s = 0;
    for (int k = 0; k < 6; k++) { v[k] = blocksums[t * 6 + k]; s += v[k]; }
    sums[t] = s;
    __syncthreads();
    for (int off = 1; off < 256; off <<= 1) {
        int x = (t >= off) ? sums[t - off] : 0;
        __syncthreads();
        sums[t] += x;
        __syncthreads();
    }
    int base = (t > 0) ? sums[t - 1] : 0;
    for (int k = 0; k < 6; k++) {
        blockbase[t * 6 + k] = base;
        base += v[k];
    }
}

__global__ __launch_bounds__(256) void add_base_kernel(
    int* __restrict__ offsets, const int* __restrict__ blockbase,
    int* __restrict__ cursors) {
    int gid = blockIdx.x * 256 + threadIdx.x;
    int o = offsets[gid] + blockbase[blockIdx.x];
    offsets[gid] = o;
    cursors[gid] = o;
}

// ---------------------------------------------------------------------------
// Phase 3: fill per-dest-pixel contributor lists (source index only).
// ---------------------------------------------------------------------------
__global__ __launch_bounds__(256) void fill_kernel(
    const float4* __restrict__ proj4, int* __restrict__ cursors,
    int* __restrict__ bins) {
    int gid = blockIdx.x * 256 + threadIdx.x;
    int bv = gid >> 16;
    int n = gid & (HW - 1);
    float4 p = proj4[gid];
    int base = bv << 16;
    for_each_tap(p, [&](int q) {
        int pos = atomicAdd(&cursors[base | q], 1);
        bins[pos] = n;
    });
}

// ---------------------------------------------------------------------------
// Transpose feats (BV,C,HW) fp32 -> featsT (BV,HW,C) fp16: each point's 32
// channels become one contiguous 64B record (one cacheline).
// ---------------------------------------------------------------------------
__global__ __launch_bounds__(256) void transpose_kernel(
    const float* __restrict__ feats, __half* __restrict__ featsT) {
    __shared__ float sm[C][257];
    int blk = blockIdx.x;
    int bv = blk >> 8;
    int n0 = (blk & 255) << 8;
    int tid = threadIdx.x;
    const float* src = feats + (size_t)bv * C * HW + n0;
#pragma unroll
    for (int c = 0; c < C; c++) sm[c][tid] = src[(size_t)c * HW + tid];
    __syncthreads();
    __half* dst = featsT + ((size_t)bv * HW + n0) * C;
#pragma unroll
    for (int pass = 0; pass < 8; pass++) {
        int nl = pass * 32 + (tid >> 3);
        int c4 = (tid & 7) << 2;
        __half2 lo = __floats2half2_rn(sm[c4][nl], sm[c4 + 1][nl]);
        __half2 hi = __floats2half2_rn(sm[c4 + 2][nl], sm[c4 + 3][nl]);
        uint2 pk;
        pk.x = *(unsigned int*)&lo;
        pk.y = *(unsigned int*)&hi;
        *(uint2*)(dst + (size_t)nl * C + c4) = pk;
    }
}

// ---------------------------------------------------------------------------
// Phase 4: gather. One thread per dest pixel; contiguous 64B fp16 feature
// records; 32 fp32 register accumulators; fused normalize + store.
// ---------------------------------------------------------------------------
__global__ __launch_bounds__(256) void gather_kernel(
    const float4* __restrict__ proj4, const __half* __restrict__ featsT,
    const int* __restrict__ counts, const int* __restrict__ offsets,
    const int* __restrict__ bins, float* __restrict__ out) {
    int gid = blockIdx.x * 256 + threadIdx.x;
    int bv = gid >> 16;
    int q = gid & (HW - 1);
    float qx = (float)(q & (W - 1));
    float qy = (float)(q >> 8);

    int cnt = counts[gid];
    int off = offsets[gid];

    const float4* pj = proj4 + ((size_t)bv << 16);
    const __half* fb = featsT + (((size_t)bv << 16)) * C;

    float wsum = 0.0f, zwsum = 0.0f;
    float facc[C];
#pragma unroll
    for (int c = 0; c < C; c++) facc[c] = 0.0f;

    for (int j = 0; j < cnt; j++) {
        int n = bins[off + j];
        float4 p = pj[n];
        float ddx = qx - p.x, ddy = qy - p.y;
        float dist = sqrtf(ddx * ddx + ddy * ddy + EPS);
        float wr = fmaxf(0.0f, 1.0f - dist * (1.0f / RADIUS));
        float w = wr * p.w;  // p.w = exp(-tau*z)
        wsum += w;
        zwsum += p.z * w;
        const uint4* fp = (const uint4*)(fb + (size_t)n * C);
#pragma unroll
        for (int g = 0; g < 4; g++) {
            uint4 v = fp[g];
            const __half2* h2 = (const __half2*)&v;
#pragma unroll
            for (int k = 0; k < 4; k++) {
                float2 f2 = __half22float2(h2[k]);
                facc[g * 8 + 2 * k]     = fmaf(w, f2.x, facc[g * 8 + 2 * k]);
                facc[g * 8 + 2 * k + 1] = fmaf(w, f2.y, facc[g * 8 + 2 * k + 1]);
            }
        }
    }

    float invw = 1.0f / (wsum + EPS);
    float* ob = out + (size_t)bv * C * HW + q;
#pragma unroll
    for (int c = 0; c < C; c++) ob[(size_t)c * HW] = facc[c] * invw;
    out[(size_t)BV * C * HW + gid] = zwsum * invw;
}

extern "C" void kernel_launch(void* const* d_in, const int* in_sizes, int n_in,
                              void* d_out, int out_size, void* d_ws, size_t ws_size,
                              hipStream_t stream) {
    const float* depths   = (const float*)d_in[0];  // (B,V,1,H,W)
    const float* feats    = (const float*)d_in[1];  // (B,V,C,H,W)
    const float* Kmat     = (const float*)d_in[2];  // (B,4,4)
    const float* srcRTinv = (const float*)d_in[4];  // (B,V,4,4)
    const float* dstRT    = (const float*)d_in[5];  // (B,1,4,4)
    float* out = (float*)d_out;

    // ws layout:
    //   proj4     : NPIX float4      6.29 MB
    //   bins      : 9*NPIX int      14.16 MB
    //   featsT    : NPIX*C __half   25.17 MB
    //   counts    : NPIX int         1.57 MB
    //   offsets   : NPIX int         1.57 MB
    //   cursors   : NPIX int         1.57 MB
    //   blocksums/blockbase/Mbuf     ~13 KB
    // total ~50.4 MB  (round-2 proved ws >= ~63 MB)
    char* ws = (char*)d_ws;
    size_t off_proj = 0;
    size_t off_bins = off_proj + (size_t)NPIX * 16;
    size_t off_featsT = off_bins + (size_t)9 * NPIX * 4;
    size_t off_counts = off_featsT + (size_t)NPIX * C * 2;
    size_t off_offsets = off_counts + (size_t)NPIX * 4;
    size_t off_cursors = off_offsets + (size_t)NPIX * 4;
    size_t off_bsums = off_cursors + (size_t)NPIX * 4;
    size_t off_bbase = off_bsums + (size_t)NBLK * 4;
    size_t off_M = off_bbase + (size_t)NBLK * 4;
    size_t needed = off_M + (size_t)BV * 16 * 4;

    if (ws_size < needed) {
        hipMemsetAsync(d_out, 0, (size_t)out_size * 4, stream);
        return;
    }

    float4* proj4  = (float4*)(ws + off_proj);
    int* bins      = (int*)(ws + off_bins);
    __half* featsT = (__half*)(ws + off_featsT);
    int* counts    = (int*)(ws + off_counts);
    int* offsets   = (int*)(ws + off_offsets);
    int* cursors   = (int*)(ws + off_cursors);
    int* blocksums = (int*)(ws + off_bsums);
    int* blockbase = (int*)(ws + off_bbase);
    float* Mbuf    = (float*)(ws + off_M);

    hipMemsetAsync(counts, 0, (size_t)NPIX * 4, stream);
    setup_kernel<<<1, 64, 0, stream>>>(Kmat, srcRTinv, dstRT, Mbuf);
    project_count_kernel<<<NBLK, 256, 0, stream>>>(depths, Mbuf, proj4, counts);
    transpose_kernel<<<NBLK, 256, 0, stream>>>(feats, featsT);
    scan_blocks_kernel<<<NBLK, 256, 0, stream>>>(counts, offsets, blocksums);
    scan_tops_kernel<<<1, 256, 0, stream>>>(blocksums, blockbase);
    add_base_kernel<<<NBLK, 256, 0, stream>>>(offsets, blockbase, cursors);
    fill_kernel<<<NBLK, 256, 0, stream>>>(proj4, cursors, bins);
    gather_kernel<<<NBLK, 256, 0, stream>>>(proj4, featsT, counts, offsets, bins, out);
}

// Round 6
// 260.562 us; speedup vs baseline: 8.3538x; 1.2140x over previous
//
#include <hip/hip_runtime.h>
#include <hip/hip_fp16.h>
#include <math.h>

#define H 256
#define W 256
#define HW (H * W)
#define B 2
#define V 3
#define BV (B * V)
#define C 32
#define RADIUS 1.5f
#define TAU 1.0f
#define EPS 1e-8f

#define NPIX (BV * HW)    // 393216 destination pixels (= source points)
#define NBLK (NPIX / 256) // 1536
#define CAP 16            // fixed slots per dest pixel (mean ~8.2)
#define OVF_CAP 65536     // exact spill list for slots >= CAP (expected empty)

// ---------------------------------------------------------------------------
// Setup: per (b,v) fold the projection chain into one matrix
//   M = K[b] * dst_RT[b] * src_RTinv[b,v] * inv(K[b])
// ---------------------------------------------------------------------------
__global__ void setup_kernel(const float* __restrict__ Kmat,
                             const float* __restrict__ srcRTinv,
                             const float* __restrict__ dstRT,
                             float* __restrict__ Mbuf) {
    int bv = threadIdx.x;
    if (bv >= BV) return;
    int b = bv / V;

    float a[4][8];
    for (int i = 0; i < 4; i++)
        for (int j = 0; j < 4; j++) {
            a[i][j] = Kmat[b * 16 + i * 4 + j];
            a[i][4 + j] = (i == j) ? 1.0f : 0.0f;
        }
    for (int col = 0; col < 4; col++) {
        int piv = col;
        float best = fabsf(a[col][col]);
        for (int r = col + 1; r < 4; r++) {
            float v = fabsf(a[r][col]);
            if (v > best) { best = v; piv = r; }
        }
        if (piv != col) {
            for (int j = 0; j < 8; j++) {
                float t = a[col][j]; a[col][j] = a[piv][j]; a[piv][j] = t;
            }
        }
        float s = 1.0f / a[col][col];
        for (int j = 0; j < 8; j++) a[col][j] *= s;
        for (int r = 0; r < 4; r++) {
            if (r == col) continue;
            float m = a[r][col];
            for (int j = 0; j < 8; j++) a[r][j] -= m * a[col][j];
        }
    }
    float Kinv[16];
    for (int i = 0; i < 4; i++)
        for (int j = 0; j < 4; j++) Kinv[i * 4 + j] = a[i][4 + j];

    float T1[16];
    const float* S = srcRTinv + bv * 16;
    for (int i = 0; i < 4; i++)
        for (int j = 0; j < 4; j++) {
            float acc = 0.0f;
            for (int k = 0; k < 4; k++) acc += S[i * 4 + k] * Kinv[k * 4 + j];
            T1[i * 4 + j] = acc;
        }
    float T2[16];
    const float* D = dstRT + b * 16;
    for (int i = 0; i < 4; i++)
        for (int j = 0; j < 4; j++) {
            float acc = 0.0f;
            for (int k = 0; k < 4; k++) acc += D[i * 4 + k] * T1[k * 4 + j];
            T2[i * 4 + j] = acc;
        }
    const float* Kb = Kmat + b * 16;
    for (int i = 0; i < 4; i++)
        for (int j = 0; j < 4; j++) {
            float acc = 0.0f;
            for (int k = 0; k < 4; k++) acc += Kb[i * 4 + k] * T2[k * 4 + j];
            Mbuf[bv * 16 + i * 4 + j] = acc;
        }
}

// ---------------------------------------------------------------------------
// Tap enumeration: visit every dest pixel q (within-image) whose reference
// weight is > 0: bounds, z>0, dist<RADIUS (d2<RADIUS^2 incl. EPS).
// ---------------------------------------------------------------------------
template <typename F>
__device__ __forceinline__ void for_each_tap(float4 p, F&& fn) {
    if (!(p.z > 0.0f)) return;
    float rx = rintf(p.x), ry = rintf(p.y);
#pragma unroll
    for (int dy = -1; dy <= 1; dy++) {
#pragma unroll
        for (int dx = -1; dx <= 1; dx++) {
            float ix = rx + (float)dx, iy = ry + (float)dy;
            if (ix >= 0.0f && ix < (float)W && iy >= 0.0f && iy < (float)H) {
                float ddx = ix - p.x, ddy = iy - p.y;
                float d2 = ddx * ddx + ddy * ddy + EPS;
                if (d2 < RADIUS * RADIUS) {
                    int q = ((int)iy << 8) | (int)ix;
                    fn(q);
                }
            }
        }
    }
}

// ---------------------------------------------------------------------------
// Phase 1: project + direct-slot fill in ONE pass.
//   slot = atomicAdd(counts[q]); slot < CAP -> bins[slot*NPIX+q] (SoA);
//   else exact spill to overflow list.
// ---------------------------------------------------------------------------
__global__ __launch_bounds__(256) void project_fill_kernel(
    const float* __restrict__ depths, const float* __restrict__ Mbuf,
    float4* __restrict__ proj4, int* __restrict__ counts,
    int* __restrict__ bins, int* __restrict__ ovf_cnt,
    int2* __restrict__ ovf) {
    int gid = blockIdx.x * 256 + threadIdx.x;
    int bv = gid >> 16;
    int n = gid & (HW - 1);
    int pxi = n & (W - 1);
    int pyi = n >> 8;

    float xn = (float)pxi * (2.0f / (W - 1)) - 1.0f;
    float yn = (float)pyi * (2.0f / (H - 1)) - 1.0f;
    float d = depths[gid];
    const float* M = Mbuf + bv * 16;
    float X = xn * d, Y = yn * d;
    float p0 = M[0] * X + M[1] * Y + M[2] * d + M[3];
    float p1 = M[4] * X + M[5] * Y + M[6] * d + M[7];
    float z  = M[8] * X + M[9] * Y + M[10] * d + M[11];

    bool zpos = z > 0.0f;
    float inv = 1.0f / (z + EPS);
    float xp = zpos ? p0 * inv : -10.0f;
    float yp = zpos ? p1 * inv : -10.0f;
    float px = (xp + 1.0f) * 0.5f * (float)(W - 1);
    float py = (yp + 1.0f) * 0.5f * (float)(H - 1);
    float wd = expf(-TAU * z);
    float4 p = make_float4(px, py, z, wd);
    proj4[gid] = p;

    int base = bv << 16;
    for_each_tap(p, [&](int q) {
        int g = base | q;
        int slot = atomicAdd(&counts[g], 1);
        if (slot < CAP) {
            bins[slot * NPIX + g] = n;
        } else {
            int o = atomicAdd(ovf_cnt, 1);
            if (o < OVF_CAP) ovf[o] = make_int2(g, n);
        }
    });
}

// ---------------------------------------------------------------------------
// Transpose feats (BV,C,HW) fp32 -> featsT (BV,HW,C) fp16: one contiguous
// 64B record per point.
// ---------------------------------------------------------------------------
__global__ __launch_bounds__(256) void transpose_kernel(
    const float* __restrict__ feats, __half* __restrict__ featsT) {
    __shared__ float sm[C][257];
    int blk = blockIdx.x;
    int bv = blk >> 8;
    int n0 = (blk & 255) << 8;
    int tid = threadIdx.x;
    const float* src = feats + (size_t)bv * C * HW + n0;
#pragma unroll
    for (int c = 0; c < C; c++) sm[c][tid] = src[(size_t)c * HW + tid];
    __syncthreads();
    __half* dst = featsT + ((size_t)bv * HW + n0) * C;
#pragma unroll
    for (int pass = 0; pass < 8; pass++) {
        int nl = pass * 32 + (tid >> 3);
        int c4 = (tid & 7) << 2;
        __half2 lo = __floats2half2_rn(sm[c4][nl], sm[c4 + 1][nl]);
        __half2 hi = __floats2half2_rn(sm[c4 + 2][nl], sm[c4 + 3][nl]);
        uint2 pk;
        pk.x = *(unsigned int*)&lo;
        pk.y = *(unsigned int*)&hi;
        *(uint2*)(dst + (size_t)nl * C + c4) = pk;
    }
}

// ---------------------------------------------------------------------------
// Phase 2: gather. One thread per dest pixel. Slot-major bins => coalesced.
// Overflow entries (cnt > CAP) are resolved exactly by scanning the spill
// list (expected empty).
// ---------------------------------------------------------------------------
__global__ __launch_bounds__(256) void gather_kernel(
    const float4* __restrict__ proj4, const __half* __restrict__ featsT,
    const int* __restrict__ counts, const int* __restrict__ bins,
    const int* __restrict__ ovf_cnt, const int2* __restrict__ ovf,
    float* __restrict__ out) {
    int gid = blockIdx.x * 256 + threadIdx.x;
    int bv = gid >> 16;
    int q = gid & (HW - 1);
    float qx = (float)(q & (W - 1));
    float qy = (float)(q >> 8);

    int cnt = counts[gid];
    int cap = min(cnt, CAP);

    const float4* pj = proj4 + ((size_t)bv << 16);
    const __half* fb = featsT + ((size_t)bv << 16) * C;

    float wsum = 0.0f, zwsum = 0.0f;
    float facc[C];
#pragma unroll
    for (int c = 0; c < C; c++) facc[c] = 0.0f;

    auto accumulate = [&](int n) {
        float4 p = pj[n];
        float ddx = qx - p.x, ddy = qy - p.y;
        float dist = sqrtf(ddx * ddx + ddy * ddy + EPS);
        float wr = fmaxf(0.0f, 1.0f - dist * (1.0f / RADIUS));
        float w = wr * p.w;  // p.w = exp(-tau*z)
        wsum += w;
        zwsum += p.z * w;
        const uint4* fp = (const uint4*)(fb + (size_t)n * C);
#pragma unroll
        for (int g = 0; g < 4; g++) {
            uint4 v = fp[g];
            const __half2* h2 = (const __half2*)&v;
#pragma unroll
            for (int k = 0; k < 4; k++) {
                float2 f2 = __half22float2(h2[k]);
                facc[g * 8 + 2 * k]     = fmaf(w, f2.x, facc[g * 8 + 2 * k]);
                facc[g * 8 + 2 * k + 1] = fmaf(w, f2.y, facc[g * 8 + 2 * k + 1]);
            }
        }
    };

    for (int j = 0; j < cap; j++) accumulate(bins[j * NPIX + gid]);

    if (cnt > CAP) {  // exact spill path; expected never taken
        int oc = min(*ovf_cnt, OVF_CAP);
        for (int i = 0; i < oc; i++) {
            int2 e = ovf[i];
            if (e.x == gid) accumulate(e.y);
        }
    }

    float invw = 1.0f / (wsum + EPS);
    float* ob = out + (size_t)bv * C * HW + q;
#pragma unroll
    for (int c = 0; c < C; c++) ob[(size_t)c * HW] = facc[c] * invw;
    out[(size_t)BV * C * HW + gid] = zwsum * invw;
}

extern "C" void kernel_launch(void* const* d_in, const int* in_sizes, int n_in,
                              void* d_out, int out_size, void* d_ws, size_t ws_size,
                              hipStream_t stream) {
    const float* depths   = (const float*)d_in[0];  // (B,V,1,H,W)
    const float* feats    = (const float*)d_in[1];  // (B,V,C,H,W)
    const float* Kmat     = (const float*)d_in[2];  // (B,4,4)
    const float* srcRTinv = (const float*)d_in[4];  // (B,V,4,4)
    const float* dstRT    = (const float*)d_in[5];  // (B,1,4,4)
    float* out = (float*)d_out;

    // ws layout:
    //   bins    : CAP*NPIX int (slot-major)  25.17 MB
    //   featsT  : NPIX*C __half              25.17 MB
    //   proj4   : NPIX float4                 6.29 MB
    //   counts  : NPIX int + ovf_cnt          1.57 MB (+4B, memset together)
    //   ovf     : OVF_CAP int2                0.52 MB
    //   Mbuf    : BV*16 float                 tiny
    // total ~58.7 MB (<= 63 MB proven available in round 2)
    char* ws = (char*)d_ws;
    size_t off_bins = 0;
    size_t off_featsT = off_bins + (size_t)CAP * NPIX * 4;
    size_t off_proj = off_featsT + (size_t)NPIX * C * 2;
    size_t off_counts = off_proj + (size_t)NPIX * 16;
    size_t off_ovfcnt = off_counts + (size_t)NPIX * 4;
    size_t off_ovf = off_ovfcnt + 16;  // keep int2 array 8B-aligned
    size_t off_M = off_ovf + (size_t)OVF_CAP * 8;
    size_t needed = off_M + (size_t)BV * 16 * 4;

    if (ws_size < needed) {
        hipMemsetAsync(d_out, 0, (size_t)out_size * 4, stream);
        return;
    }

    int* bins      = (int*)(ws + off_bins);
    __half* featsT = (__half*)(ws + off_featsT);
    float4* proj4  = (float4*)(ws + off_proj);
    int* counts    = (int*)(ws + off_counts);
    int* ovf_cnt   = (int*)(ws + off_ovfcnt);
    int2* ovf      = (int2*)(ws + off_ovf);
    float* Mbuf    = (float*)(ws + off_M);

    // zero counts + overflow cursor in one memset (adjacent)
    hipMemsetAsync(counts, 0, (size_t)NPIX * 4 + 16, stream);
    setup_kernel<<<1, 64, 0, stream>>>(Kmat, srcRTinv, dstRT, Mbuf);
    project_fill_kernel<<<NBLK, 256, 0, stream>>>(depths, Mbuf, proj4, counts,
                                                  bins, ovf_cnt, ovf);
    transpose_kernel<<<NBLK, 256, 0, stream>>>(feats, featsT);
    gather_kernel<<<NBLK, 256, 0, stream>>>(proj4, featsT, counts, bins,
                                            ovf_cnt, ovf, out);
}